// Round 8
// baseline (138.968 us; speedup 1.0000x reference)
//
#include <hip/hip_runtime.h>
#include <math.h>

#define R_DIM 5
#define A_DIM 8
#define K0    8
#define KK    7
#define TPB   128
#define TASKS_PER_BLOCK 64

// code[n] = (rank<<4) | original_index   (rank 1..7, idx 0..7)
#define ORK(n) (code[(n)] >> 4)
#define OID(n) (code[(n)] & 15)

// One pair evaluation (p,q compile-time). Float expressions bitwise-match the
// reference elementwise order (validated rounds 2/3/5/6). det uses
// (vy[j]*m2 - vx[j]*m1) + ajs[j]*m3 == (ajx*m1 - ajy*m2) + ajs*m3 bitwise,
// since ajx = -vx, ajy = -vy exactly (IEEE sub antisymmetry).
#define DO_PAIR(p, q) do {                                                    \
    float d01 = vx[(p)]*vx[(q)] + vy[(p)]*vy[(q)];                            \
    float den = d00[(p)]*d00[(q)] - d01*d01;                                  \
    float inv = 1.0f/den;                                                     \
    float u   = (d00[(q)]*d02[(p)] - d01*d02[(q)]) * inv;                     \
    float w   = (d00[(p)]*d02[(q)] - d01*d02[(p)]) * inv;                     \
    float w0a = (1.0f - u) - w;                                               \
    float w0b = (1.0f - w) - u;                                               \
    float dmnP = INF, dmxP = -INF;                                            \
    _Pragma("unroll")                                                         \
    for (int j = 0; j < KK; ++j) {                                            \
        if (j == (p) || j == (q)) continue;  /* compile-time pruned */        \
        float bx = ox[(p)]-ox[j], by = oy[(p)]-oy[j], bs = osq[(p)]-osq[j];   \
        float dx = ox[(q)]-ox[j], dy = oy[(q)]-oy[j], ds = osq[(q)]-osq[j];   \
        float m1 = by*ds - bs*dy;                                             \
        float m2 = bx*ds - bs*dx;                                             \
        float m3 = bx*dy - by*dx;                                             \
        float det = (vy[j]*m2 - vx[j]*m1) + ajs[j]*m3;                        \
        dmnP = fminf(dmnP, det);                                              \
        dmxP = fmaxf(dmxP, det);                                              \
    }                                                                         \
    bool posuw = (u > 0.0f) && (w > 0.0f);                                    \
    bool okA = (dmxP <= 0.0f);                                                \
    bool okB = (dmnP >= 0.0f);                                                \
    float muw = fmaxf(u*u, w*w);                                              \
    float scA = fmaxf(w0a*w0a, muw);                                          \
    float scB = fmaxf(w0b*w0b, muw);                                          \
    int rpq = ORK(p)*8 + ORK(q);                                              \
    int rqp = ORK(q)*8 + ORK(p);                                              \
    bool vA = okA && posuw && (w0a > 0.0f) && (scA < INF);                    \
    bool tA = vA && (scA < bsc || (scA == bsc && rpq < brij));                \
    bsc = tA ? scA : bsc;  brij = tA ? rpq : brij;                            \
    bw0 = tA ? w0a : bw0;  bw2 = tA ? u : bw2;  bw1 = tA ? w : bw1;           \
    bi  = tA ? OID(p) : bi;  bj = tA ? OID(q) : bj;                           \
    bool vB = okB && posuw && (w0b > 0.0f) && (scB < INF);                    \
    bool tB = vB && (scB < bsc || (scB == bsc && rqp < brij));                \
    bsc = tB ? scB : bsc;  brij = tB ? rqp : brij;                            \
    bw0 = tB ? w0b : bw0;  bw2 = tB ? w : bw2;  bw1 = tB ? u : bw1;           \
    bi  = tB ? OID(q) : bi;  bj = tB ? OID(p) : bj;                           \
} while (0)

__global__ __launch_bounds__(TPB)
__attribute__((amdgpu_waves_per_eu(4)))
void bc_kernel(
    const float* __restrict__ tmpl,
    const float* __restrict__ proj,
    float* __restrict__ out,
    int ntask)
{
#pragma clang fp contract(off)
    const float INF = __builtin_inff();

    __shared__ unsigned long long skey[2][TASKS_PER_BLOCK];
    __shared__ float sw0[2][TASKS_PER_BLOCK];
    __shared__ float sw2[2][TASKS_PER_BLOCK];
    __shared__ float sw1[2][TASKS_PER_BLOCK];
    __shared__ int   sbi[2][TASKS_PER_BLOCK];
    __shared__ int   sbj[2][TASKS_PER_BLOCK];

    int lane = threadIdx.x & 63;
    int wid  = threadIdx.x >> 6;
    int task = blockIdx.x * TASKS_PER_BLOCK + lane;   // grid sized exactly
    int v  = task / (R_DIM * A_DIM);
    int ra = task - v * (R_DIM * A_DIM);

    float tx = tmpl[ra * 2 + 0];
    float ty = tmpl[ra * 2 + 1];

    // ---- preamble (duplicated across the 2 waves; same 64 tasks) ----
    const float4* pv4 = reinterpret_cast<const float4*>(proj + (size_t)v * (K0 * 2));
    float4 q0 = pv4[0], q1 = pv4[1], q2 = pv4[2], q3 = pv4[3];
    float px[K0] = {q0.x, q0.z, q1.x, q1.z, q2.x, q2.z, q3.x, q3.z};
    float py[K0] = {q0.y, q0.w, q1.y, q1.w, q2.y, q2.w, q3.y, q3.w};
    float ps[K0], pd[K0];
#pragma unroll
    for (int k = 0; k < K0; ++k) {
        ps[k] = px[k] * px[k] + py[k] * py[k];
        float dx = tx - px[k], dy = ty - py[k];
        pd[k] = sqrtf(dx * dx + dy * dy);
    }

    int rank[K0];
#pragma unroll
    for (int k = 0; k < K0; ++k) {
        int r = 0;
#pragma unroll
        for (int l = 0; l < K0; ++l)
            r += (pd[l] < pd[k] || (pd[l] == pd[k] && l < k)) ? 1 : 0;
        rank[k] = r;
    }

    float cx = 0.f, cy = 0.f, cs = 0.f; int cidx = 0;
#pragma unroll
    for (int k = 0; k < K0; ++k) {
        bool h = (rank[k] == 0);
        cx = h ? px[k] : cx;  cy = h ? py[k] : cy;
        cs = h ? ps[k] : cs;  cidx = h ? k : cidx;
    }

    float ox[KK], oy[KK], osq[KK]; int code[KK];
#pragma unroll
    for (int n = 0; n < KK; ++n) {
        bool ge = (n >= cidx);
        ox[n]  = ge ? px[n + 1]   : px[n];
        oy[n]  = ge ? py[n + 1]   : py[n];
        osq[n] = ge ? ps[n + 1]   : ps[n];
        int rk = ge ? rank[n + 1] : rank[n];   // 1..7, distinct
        int id = ge ? (n + 1)     : n;
        code[n] = (rk << 4) | id;
    }

    float v2x = tx - cx, v2y = ty - cy;
    float vx[KK], vy[KK], d00[KK], d02[KK], ajs[KK];
#pragma unroll
    for (int n = 0; n < KK; ++n) {
        vx[n] = ox[n] - cx;
        vy[n] = oy[n] - cy;
        d00[n] = vx[n] * vx[n] + vy[n] * vy[n];
        d02[n] = vx[n] * v2x + vy[n] * v2y;
        ajs[n] = cs - osq[n];
    }

    // ---- per-wave compile-time pair subset (wave-uniform branch) ----
    float bsc = INF; int brij = 0x7fffffff;
    float bw0 = 0.f, bw1 = 0.f, bw2 = 0.f;
    int bi = 0, bj = 0;

    if (wid == 0) {
        DO_PAIR(0,1); DO_PAIR(0,2); DO_PAIR(0,3); DO_PAIR(0,4);
        DO_PAIR(0,5); DO_PAIR(0,6); DO_PAIR(1,2); DO_PAIR(1,3);
        DO_PAIR(1,4); DO_PAIR(1,5); DO_PAIR(1,6);
    } else {
        DO_PAIR(2,3); DO_PAIR(2,4); DO_PAIR(2,5); DO_PAIR(2,6);
        DO_PAIR(3,4); DO_PAIR(3,5); DO_PAIR(3,6); DO_PAIR(4,5);
        DO_PAIR(4,6); DO_PAIR(5,6);
    }

    // ---- publish wave candidate; cross-wave reduce via LDS ----
    unsigned long long key =
        ((unsigned long long)__float_as_uint(bsc) << 32) | (unsigned int)brij;
    skey[wid][lane] = key;
    sw0[wid][lane] = bw0;
    sw2[wid][lane] = bw2;
    sw1[wid][lane] = bw1;
    sbi[wid][lane] = bi;
    sbj[wid][lane] = bj;
    __syncthreads();

    if (wid == 0) {
        unsigned long long mk = skey[0][lane]; int ws = 0;
        unsigned long long k1 = skey[1][lane];
        if (k1 < mk) { mk = k1; ws = 1; }
        bool found = ((unsigned int)(mk >> 32)) != 0x7f800000u;

        int sec = 0;   // fallback: rank-1 other's original index
#pragma unroll
        for (int n = 0; n < KK; ++n) sec = (ORK(n) == 1) ? OID(n) : sec;

        float o0 = found ? sw0[ws][lane] : 0.0f;
        float o1 = found ? sw2[ws][lane] : 0.0f;
        float o2 = found ? sw1[ws][lane] : 0.0f;
        int j1 = found ? sbi[ws][lane] : sec;
        int j2 = found ? sbj[ws][lane] : sec;

        size_t ob = (size_t)task * 3;
        out[ob + 0] = o0;
        out[ob + 1] = o1;
        out[ob + 2] = o2;
        size_t off = (size_t)ntask * 3;
        out[off + ob + 0] = (float)cidx;
        out[off + ob + 1] = (float)j1;
        out[off + ob + 2] = (float)j2;
    }
}

extern "C" void kernel_launch(void* const* d_in, const int* in_sizes, int n_in,
                              void* d_out, int out_size, void* d_ws, size_t ws_size,
                              hipStream_t stream) {
    const float* tmpl = (const float*)d_in[0];   // (5, 8, 2) float32
    const float* proj = (const float*)d_in[1];   // (5000, 8, 2) float32
    float* out = (float*)d_out;                  // [V*R*A*3 weights][V*R*A*3 indices]

    int V = in_sizes[1] / (K0 * 2);
    int ntask = V * R_DIM * A_DIM;                 // 200000 = 3125 * 64
    int blocks = (ntask + TASKS_PER_BLOCK - 1) / TASKS_PER_BLOCK;
    bc_kernel<<<blocks, TPB, 0, stream>>>(tmpl, proj, out, ntask);
}

// Round 9
// 82.610 us; speedup vs baseline: 1.6822x; 1.6822x over previous
//
#include <hip/hip_runtime.h>
#include <math.h>

#define R_DIM 5
#define A_DIM 8
#define K0    8
#define KK    7
#define TPB   128
#define TASKS_PER_BLOCK 64

// code[n] = (rank<<4) | original_index   (rank 1..7, idx 0..7)
#define ORK(n) (code[(n)] >> 4)
#define OID(n) (code[(n)] & 15)

// One pair evaluation (p,q compile-time). Float expressions bitwise-match the
// reference elementwise order (validated rounds 2/3/5/6/8). det uses
// (vy[j]*m2 - vx[j]*m1) + ajs[j]*m3 == (ajx*m1 - ajy*m2) + ajs*m3 bitwise,
// since ajx = -vx, ajy = -vy exactly (IEEE sub antisymmetry).
#define DO_PAIR(p, q) do {                                                    \
    float d01 = vx[(p)]*vx[(q)] + vy[(p)]*vy[(q)];                            \
    float den = d00[(p)]*d00[(q)] - d01*d01;                                  \
    float inv = 1.0f/den;                                                     \
    float u   = (d00[(q)]*d02[(p)] - d01*d02[(q)]) * inv;                     \
    float w   = (d00[(p)]*d02[(q)] - d01*d02[(p)]) * inv;                     \
    float w0a = (1.0f - u) - w;                                               \
    float w0b = (1.0f - w) - u;                                               \
    float dmnP = INF, dmxP = -INF;                                            \
    _Pragma("unroll")                                                         \
    for (int j = 0; j < KK; ++j) {                                            \
        if (j == (p) || j == (q)) continue;  /* compile-time pruned */        \
        float bx = ox[(p)]-ox[j], by = oy[(p)]-oy[j], bs = osq[(p)]-osq[j];   \
        float dx = ox[(q)]-ox[j], dy = oy[(q)]-oy[j], ds = osq[(q)]-osq[j];   \
        float m1 = by*ds - bs*dy;                                             \
        float m2 = bx*ds - bs*dx;                                             \
        float m3 = bx*dy - by*dx;                                             \
        float det = (vy[j]*m2 - vx[j]*m1) + ajs[j]*m3;                        \
        dmnP = fminf(dmnP, det);                                              \
        dmxP = fmaxf(dmxP, det);                                              \
    }                                                                         \
    bool posuw = (u > 0.0f) && (w > 0.0f);                                    \
    bool okA = (dmxP <= 0.0f);                                                \
    bool okB = (dmnP >= 0.0f);                                                \
    float muw = fmaxf(u*u, w*w);                                              \
    float scA = fmaxf(w0a*w0a, muw);                                          \
    float scB = fmaxf(w0b*w0b, muw);                                          \
    int rpq = ORK(p)*8 + ORK(q);                                              \
    int rqp = ORK(q)*8 + ORK(p);                                              \
    bool vA = okA && posuw && (w0a > 0.0f) && (scA < INF);                    \
    bool tA = vA && (scA < bsc || (scA == bsc && rpq < brij));                \
    bsc = tA ? scA : bsc;  brij = tA ? rpq : brij;                            \
    bw0 = tA ? w0a : bw0;  bw2 = tA ? u : bw2;  bw1 = tA ? w : bw1;           \
    bi  = tA ? OID(p) : bi;  bj = tA ? OID(q) : bj;                           \
    bool vB = okB && posuw && (w0b > 0.0f) && (scB < INF);                    \
    bool tB = vB && (scB < bsc || (scB == bsc && rqp < brij));                \
    bsc = tB ? scB : bsc;  brij = tB ? rqp : brij;                            \
    bw0 = tB ? w0b : bw0;  bw2 = tB ? w : bw2;  bw1 = tB ? u : bw1;           \
    bi  = tB ? OID(q) : bi;  bj = tB ? OID(p) : bj;                           \
} while (0)

__global__ __launch_bounds__(TPB)
__attribute__((amdgpu_num_vgpr(128)))
void bc_kernel(
    const float* __restrict__ tmpl,
    const float* __restrict__ proj,
    float* __restrict__ out,
    int ntask)
{
#pragma clang fp contract(off)
    const float INF = __builtin_inff();

    __shared__ unsigned long long skey[2][TASKS_PER_BLOCK];
    __shared__ float sw0[2][TASKS_PER_BLOCK];
    __shared__ float sw2[2][TASKS_PER_BLOCK];
    __shared__ float sw1[2][TASKS_PER_BLOCK];
    __shared__ int   sbi[2][TASKS_PER_BLOCK];
    __shared__ int   sbj[2][TASKS_PER_BLOCK];

    int lane = threadIdx.x & 63;
    int wid  = threadIdx.x >> 6;
    int task = blockIdx.x * TASKS_PER_BLOCK + lane;   // grid sized exactly
    int v  = task / (R_DIM * A_DIM);
    int ra = task - v * (R_DIM * A_DIM);

    float tx = tmpl[ra * 2 + 0];
    float ty = tmpl[ra * 2 + 1];

    // ---- preamble (duplicated across the 2 waves; same 64 tasks) ----
    const float4* pv4 = reinterpret_cast<const float4*>(proj + (size_t)v * (K0 * 2));
    float4 q0 = pv4[0], q1 = pv4[1], q2 = pv4[2], q3 = pv4[3];
    float px[K0] = {q0.x, q0.z, q1.x, q1.z, q2.x, q2.z, q3.x, q3.z};
    float py[K0] = {q0.y, q0.w, q1.y, q1.w, q2.y, q2.w, q3.y, q3.w};
    float ps[K0], pd[K0];
#pragma unroll
    for (int k = 0; k < K0; ++k) {
        ps[k] = px[k] * px[k] + py[k] * py[k];
        float dx = tx - px[k], dy = ty - py[k];
        pd[k] = sqrtf(dx * dx + dy * dy);
    }

    int rank[K0];
#pragma unroll
    for (int k = 0; k < K0; ++k) {
        int r = 0;
#pragma unroll
        for (int l = 0; l < K0; ++l)
            r += (pd[l] < pd[k] || (pd[l] == pd[k] && l < k)) ? 1 : 0;
        rank[k] = r;
    }

    float cx = 0.f, cy = 0.f, cs = 0.f; int cidx = 0;
#pragma unroll
    for (int k = 0; k < K0; ++k) {
        bool h = (rank[k] == 0);
        cx = h ? px[k] : cx;  cy = h ? py[k] : cy;
        cs = h ? ps[k] : cs;  cidx = h ? k : cidx;
    }

    float ox[KK], oy[KK], osq[KK]; int code[KK];
#pragma unroll
    for (int n = 0; n < KK; ++n) {
        bool ge = (n >= cidx);
        ox[n]  = ge ? px[n + 1]   : px[n];
        oy[n]  = ge ? py[n + 1]   : py[n];
        osq[n] = ge ? ps[n + 1]   : ps[n];
        int rk = ge ? rank[n + 1] : rank[n];   // 1..7, distinct
        int id = ge ? (n + 1)     : n;
        code[n] = (rk << 4) | id;
    }

    float v2x = tx - cx, v2y = ty - cy;
    float vx[KK], vy[KK], d00[KK], d02[KK], ajs[KK];
#pragma unroll
    for (int n = 0; n < KK; ++n) {
        vx[n] = ox[n] - cx;
        vy[n] = oy[n] - cy;
        d00[n] = vx[n] * vx[n] + vy[n] * vy[n];
        d02[n] = vx[n] * v2x + vy[n] * v2y;
        ajs[n] = cs - osq[n];
    }

    // ---- per-wave compile-time pair subset (wave-uniform branch) ----
    float bsc = INF; int brij = 0x7fffffff;
    float bw0 = 0.f, bw1 = 0.f, bw2 = 0.f;
    int bi = 0, bj = 0;

    if (wid == 0) {
        DO_PAIR(0,1); DO_PAIR(0,2); DO_PAIR(0,3); DO_PAIR(0,4);
        DO_PAIR(0,5); DO_PAIR(0,6); DO_PAIR(1,2); DO_PAIR(1,3);
        DO_PAIR(1,4); DO_PAIR(1,5); DO_PAIR(1,6);
    } else {
        DO_PAIR(2,3); DO_PAIR(2,4); DO_PAIR(2,5); DO_PAIR(2,6);
        DO_PAIR(3,4); DO_PAIR(3,5); DO_PAIR(3,6); DO_PAIR(4,5);
        DO_PAIR(4,6); DO_PAIR(5,6);
    }

    // ---- publish wave candidate; cross-wave reduce via LDS ----
    unsigned long long key =
        ((unsigned long long)__float_as_uint(bsc) << 32) | (unsigned int)brij;
    skey[wid][lane] = key;
    sw0[wid][lane] = bw0;
    sw2[wid][lane] = bw2;
    sw1[wid][lane] = bw1;
    sbi[wid][lane] = bi;
    sbj[wid][lane] = bj;
    __syncthreads();

    if (wid == 0) {
        unsigned long long mk = skey[0][lane]; int ws = 0;
        unsigned long long k1 = skey[1][lane];
        if (k1 < mk) { mk = k1; ws = 1; }
        bool found = ((unsigned int)(mk >> 32)) != 0x7f800000u;

        int sec = 0;   // fallback: rank-1 other's original index
#pragma unroll
        for (int n = 0; n < KK; ++n) sec = (ORK(n) == 1) ? OID(n) : sec;

        float o0 = found ? sw0[ws][lane] : 0.0f;
        float o1 = found ? sw2[ws][lane] : 0.0f;
        float o2 = found ? sw1[ws][lane] : 0.0f;
        int j1 = found ? sbi[ws][lane] : sec;
        int j2 = found ? sbj[ws][lane] : sec;

        size_t ob = (size_t)task * 3;
        out[ob + 0] = o0;
        out[ob + 1] = o1;
        out[ob + 2] = o2;
        size_t off = (size_t)ntask * 3;
        out[off + ob + 0] = (float)cidx;
        out[off + ob + 1] = (float)j1;
        out[off + ob + 2] = (float)j2;
    }
}

extern "C" void kernel_launch(void* const* d_in, const int* in_sizes, int n_in,
                              void* d_out, int out_size, void* d_ws, size_t ws_size,
                              hipStream_t stream) {
    const float* tmpl = (const float*)d_in[0];   // (5, 8, 2) float32
    const float* proj = (const float*)d_in[1];   // (5000, 8, 2) float32
    float* out = (float*)d_out;                  // [V*R*A*3 weights][V*R*A*3 indices]

    int V = in_sizes[1] / (K0 * 2);
    int ntask = V * R_DIM * A_DIM;                 // 200000 = 3125 * 64
    int blocks = (ntask + TASKS_PER_BLOCK - 1) / TASKS_PER_BLOCK;
    bc_kernel<<<blocks, TPB, 0, stream>>>(tmpl, proj, out, ntask);
}